// Round 3
// baseline (345.690 us; speedup 1.0000x reference)
//
#include <hip/hip_runtime.h>
#include <stdint.h>
#include <math.h>

// ---------------------------------------------------------------------------
// GAT + PairNorm + ReLU, MI355X (gfx950).  Round 3.
// DIAGNOSIS from R1/R2: inputs/outputs are FLOAT32 (reference dtype), not
// bf16. Reading fp32 as bf16 pairs produced NaN (R2) which fmaxf-flushed to
// all zeros in R1 (absmax == stub's 0.62890625 exactly).
// Pipeline: fp32 in -> bf16 (dropout-folded) -> MFMA GEMM -> bf16 h ->
// fp32 attention/aggregate/PairNorm -> fp32 out.
// RNG: JAX partitionable threefry (fold-like split; bits = o0^o1).
// ---------------------------------------------------------------------------

#define N_NODES 30000
#define MPAD    30080
#define DIM     512
#define NEDGE   300000
#define ETOT    330000

typedef unsigned int u32;
typedef unsigned short u16;

typedef __attribute__((ext_vector_type(8))) short bf16x8;
typedef __attribute__((ext_vector_type(4))) float f32x4;

// ----------------------------- threefry2x32 --------------------------------
__host__ __device__ __forceinline__ void threefry2x32(u32 k0, u32 k1, u32 x0, u32 x1,
                                                      u32& o0, u32& o1) {
  u32 ks2 = k0 ^ k1 ^ 0x1BD11BDAu;
#define TF_R(r) { x0 += x1; x1 = (x1 << r) | (x1 >> (32 - r)); x1 ^= x0; }
  x0 += k0; x1 += k1;
  TF_R(13) TF_R(15) TF_R(26) TF_R(6)
  x0 += k1; x1 += ks2 + 1u;
  TF_R(17) TF_R(29) TF_R(16) TF_R(24)
  x0 += ks2; x1 += k0 + 2u;
  TF_R(13) TF_R(15) TF_R(26) TF_R(6)
  x0 += k0; x1 += k1 + 3u;
  TF_R(17) TF_R(29) TF_R(16) TF_R(24)
  x0 += k1; x1 += ks2 + 4u;
  TF_R(13) TF_R(15) TF_R(26) TF_R(6)
  x0 += ks2; x1 += k0 + 5u;
#undef TF_R
  o0 = x0; o1 = x1;
}

__device__ __forceinline__ u32 tf_fold(u32 k0, u32 k1, u32 idx) {
  u32 a, b;
  threefry2x32(k0, k1, 0u, idx, a, b);
  return a ^ b;
}

__device__ __forceinline__ float bf2f(u32 bits16) {
  return __uint_as_float(bits16 << 16);
}
__device__ __forceinline__ u16 f2bf(float f) {   // RNE
  u32 u = __float_as_uint(f);
  return (u16)((u + 0x7fffu + ((u >> 16) & 1u)) >> 16);
}

// ------------------- K0: W (fp32) -> Wt (bf16, transposed) -----------------
__global__ __launch_bounds__(256) void k_cvtW(const float* __restrict__ W,
                                              u16* __restrict__ Wt) {
  __shared__ u16 tile[32][33];
  int b = blockIdx.x;
  int bk = (b & 15) * 32, bn = (b >> 4) * 32;
  int c = threadIdx.x & 31, r = threadIdx.x >> 5;
#pragma unroll
  for (int rr = 0; rr < 32; rr += 8)
    tile[r + rr][c] = f2bf(W[(size_t)(bk + r + rr) * DIM + bn + c]);
  __syncthreads();
#pragma unroll
  for (int rr = 0; rr < 32; rr += 8)
    Wt[(size_t)(bn + r + rr) * DIM + bk + c] = tile[c][r + rr];
}

// ------------- K1: feature dropout (p=0.5) fp32 -> bf16, pad ---------------
__global__ __launch_bounds__(256) void k_dropout(const float* __restrict__ x,
                                                 u16* __restrict__ xd,
                                                 u32 kf0, u32 kf1) {
  size_t gid = (size_t)blockIdx.x * 256 + threadIdx.x;
  size_t i0 = gid * 8;
  if (i0 >= (size_t)MPAD * DIM) return;
  uint4 o = make_uint4(0u, 0u, 0u, 0u);
  if (i0 < (size_t)N_NODES * DIM) {
    float4 v0 = *(const float4*)(x + i0);
    float4 v1 = *(const float4*)(x + i0 + 4);
    float xv[8] = {v0.x, v0.y, v0.z, v0.w, v1.x, v1.y, v1.z, v1.w};
    u32 res[4];
#pragma unroll
    for (int p = 0; p < 4; p++) {
      u32 b0 = tf_fold(kf0, kf1, (u32)i0 + 2 * p);
      u32 b1 = tf_fold(kf0, kf1, (u32)i0 + 2 * p + 1);
      u32 r0 = (b0 >> 31) ? 0u : (u32)f2bf(2.0f * xv[2 * p]);     // keep <=> u<0.5
      u32 r1 = (b1 >> 31) ? 0u : (u32)f2bf(2.0f * xv[2 * p + 1]);
      res[p] = r0 | (r1 << 16);
    }
    o = make_uint4(res[0], res[1], res[2], res[3]);
  }
  *(uint4*)(xd + i0) = o;
}

// ------------------------------ K2: GEMM -----------------------------------
// h[m][n] = sum_k xd[m][k]*Wt[n][k]  (gemm_bt). 128x128 tile, 4 waves,
// 16x16x32 bf16 MFMA, register->LDS staging. h stored bf16.
__global__ __launch_bounds__(256) void k_gemm(const u16* __restrict__ A,
                                              const u16* __restrict__ B,
                                              u16* __restrict__ H) {
  __shared__ __align__(16) u16 lA[128 * 32];
  __shared__ __align__(16) u16 lB[128 * 32];
  const int bn = (blockIdx.x & 3) * 128;
  const int bm = (blockIdx.x >> 2) * 128;
  const int tid = threadIdx.x;
  const int wave = tid >> 6, lane = tid & 63;
  const int quad = lane >> 4, l16 = lane & 15;
  const int wrow = (wave & 1) * 64, wcol = (wave >> 1) * 64;

  f32x4 acc[4][4] = {};
  const int srow = tid >> 2;
  const int scq  = (tid & 3) * 8;

  for (int k0 = 0; k0 < DIM; k0 += 32) {
    uint4 va0 = *(const uint4*)(A + (size_t)(bm + srow) * DIM + k0 + scq);
    uint4 va1 = *(const uint4*)(A + (size_t)(bm + 64 + srow) * DIM + k0 + scq);
    uint4 vb0 = *(const uint4*)(B + (size_t)(bn + srow) * DIM + k0 + scq);
    uint4 vb1 = *(const uint4*)(B + (size_t)(bn + 64 + srow) * DIM + k0 + scq);
    __syncthreads();
    *(uint4*)(lA + srow * 32 + scq) = va0;
    *(uint4*)(lA + (64 + srow) * 32 + scq) = va1;
    *(uint4*)(lB + srow * 32 + scq) = vb0;
    *(uint4*)(lB + (64 + srow) * 32 + scq) = vb1;
    __syncthreads();

    bf16x8 af[4], bfr[4];
#pragma unroll
    for (int i = 0; i < 4; i++)
      af[i] = *(const bf16x8*)(lA + (wrow + i * 16 + l16) * 32 + quad * 8);
#pragma unroll
    for (int j = 0; j < 4; j++)
      bfr[j] = *(const bf16x8*)(lB + (wcol + j * 16 + l16) * 32 + quad * 8);
#pragma unroll
    for (int i = 0; i < 4; i++)
#pragma unroll
      for (int j = 0; j < 4; j++)
        acc[i][j] = __builtin_amdgcn_mfma_f32_16x16x32_bf16(af[i], bfr[j], acc[i][j], 0, 0, 0);
  }
  // C/D: col = lane&15, row = quad*4 + reg  [m89-verified]
#pragma unroll
  for (int i = 0; i < 4; i++) {
#pragma unroll
    for (int r = 0; r < 4; r++) {
      int row = bm + wrow + i * 16 + quad * 4 + r;
      u16* hp = H + (size_t)row * DIM + bn + wcol + l16;
#pragma unroll
      for (int j = 0; j < 4; j++) hp[j * 16] = f2bf(acc[i][j][r]);
    }
  }
}

// ---------------- K3: per-row attention dots a_s, a_d ----------------------
__global__ __launch_bounds__(256) void k_rowdots(const u16* __restrict__ h,
                                                 const float* __restrict__ atts,
                                                 const float* __restrict__ attd,
                                                 float* __restrict__ a_s,
                                                 float* __restrict__ a_d) {
  int row = blockIdx.x * 4 + (threadIdx.x >> 6);
  if (row >= N_NODES) return;
  int lane = threadIdx.x & 63;
  uint4 hv = *(const uint4*)(h + (size_t)row * DIM + lane * 8);
  float4 s0 = *(const float4*)(atts + lane * 8);
  float4 s1 = *(const float4*)(atts + lane * 8 + 4);
  float4 d0 = *(const float4*)(attd + lane * 8);
  float4 d1 = *(const float4*)(attd + lane * 8 + 4);
  u32 hw[4] = {hv.x, hv.y, hv.z, hv.w};
  float sa[8] = {s0.x, s0.y, s0.z, s0.w, s1.x, s1.y, s1.z, s1.w};
  float da[8] = {d0.x, d0.y, d0.z, d0.w, d1.x, d1.y, d1.z, d1.w};
  float ps = 0.f, pd = 0.f;
#pragma unroll
  for (int p = 0; p < 4; p++) {
    float h0 = bf2f(hw[p] & 0xffffu), h1 = bf2f(hw[p] >> 16);
    ps += h0 * sa[2 * p] + h1 * sa[2 * p + 1];
    pd += h0 * da[2 * p] + h1 * da[2 * p + 1];
  }
#pragma unroll
  for (int d = 1; d < 64; d <<= 1) { ps += __shfl_xor(ps, d); pd += __shfl_xor(pd, d); }
  if (lane == 0) { a_s[row] = ps; a_d[row] = pd; }
}

// -------------------- K4/K5/K6: counting sort by dst -----------------------
__global__ __launch_bounds__(256) void k_hist(const int* __restrict__ ei,
                                              int* __restrict__ counts) {
  int i = blockIdx.x * 256 + threadIdx.x;
  if (i >= ETOT) return;
  int d = (i < NEDGE) ? ei[NEDGE + i] : (i - NEDGE);
  atomicAdd(&counts[d], 1);
}

__global__ __launch_bounds__(1024) void k_scan(const int* __restrict__ counts,
                                               int* __restrict__ off,
                                               int* __restrict__ cursor) {
  __shared__ int wsum[16];
  __shared__ int s_total;
  int tid = threadIdx.x, lane = tid & 63, wid = tid >> 6;
  int carry = 0;
  for (int base = 0; base < N_NODES; base += 1024) {
    int i = base + tid;
    int v = (i < N_NODES) ? counts[i] : 0;
    int x = v;
#pragma unroll
    for (int d = 1; d < 64; d <<= 1) {
      int y = __shfl_up(x, d);
      if (lane >= d) x += y;
    }
    if (lane == 63) wsum[wid] = x;
    __syncthreads();
    if (tid == 0) {
      int run = 0;
#pragma unroll
      for (int w = 0; w < 16; w++) { int tv = wsum[w]; wsum[w] = run; run += tv; }
      s_total = run;
    }
    __syncthreads();
    int excl = x - v + wsum[wid] + carry;
    if (i < N_NODES) { off[i] = excl; cursor[i] = excl; }
    carry += s_total;
    __syncthreads();
  }
  if (tid == 0) off[N_NODES] = carry;
}

__global__ __launch_bounds__(256) void k_scatter(const int* __restrict__ ei,
                                                 int* __restrict__ cursor,
                                                 int* __restrict__ perm) {
  int i = blockIdx.x * 256 + threadIdx.x;
  if (i >= ETOT) return;
  int d = (i < NEDGE) ? ei[NEDGE + i] : (i - NEDGE);
  int slot = atomicAdd(&cursor[d], 1);
  perm[slot] = i;
}

// -------- K7: segment softmax + attention dropout + aggregation ------------
__global__ __launch_bounds__(256) void k_aggregate(
    const int* __restrict__ ei, const int* __restrict__ off, const int* __restrict__ perm,
    const float* __restrict__ a_s, const float* __restrict__ a_d,
    const u16* __restrict__ h, const float* __restrict__ bias,
    float* __restrict__ oa, u32 ka0, u32 ka1) {
  int node = blockIdx.x * 4 + (threadIdx.x >> 6);
  if (node >= N_NODES) return;
  int lane = threadIdx.x & 63;
  int beg = off[node], end = off[node + 1];
  float adn = a_d[node];

  float mx = -3.0e38f;
  for (int base = beg; base < end; base += 64) {
    int idx = base + lane;
    if (idx < end) {
      int eid = perm[idx];
      int s = (eid < NEDGE) ? ei[eid] : (eid - NEDGE);
      float lg = a_s[s] + adn;
      lg = (lg < 0.f) ? 0.2f * lg : lg;
      mx = fmaxf(mx, lg);
    }
  }
#pragma unroll
  for (int d = 1; d < 64; d <<= 1) mx = fmaxf(mx, __shfl_xor(mx, d));

  float ssum = 0.f;
  for (int base = beg; base < end; base += 64) {
    int idx = base + lane;
    if (idx < end) {
      int eid = perm[idx];
      int s = (eid < NEDGE) ? ei[eid] : (eid - NEDGE);
      float lg = a_s[s] + adn;
      lg = (lg < 0.f) ? 0.2f * lg : lg;
      ssum += expf(lg - mx);
    }
  }
#pragma unroll
  for (int d = 1; d < 64; d <<= 1) ssum += __shfl_xor(ssum, d);
  float inv_s = 2.5f / (ssum + 1e-16f);   // folds 1/(1-0.6) dropout scale

  float acc[8] = {0.f, 0.f, 0.f, 0.f, 0.f, 0.f, 0.f, 0.f};
  for (int base = beg; base < end; base += 64) {
    int idx = base + lane;
    float w = 0.f; int s = 0;
    if (idx < end) {
      int eid = perm[idx];
      s = (eid < NEDGE) ? ei[eid] : (eid - NEDGE);
      float lg = a_s[s] + adn;
      lg = (lg < 0.f) ? 0.2f * lg : lg;
      float ee = expf(lg - mx);
      u32 bits = tf_fold(ka0, ka1, (u32)eid);
      if ((bits >> 9) < 3355444u) w = ee * inv_s;  // u < float32(0.4)
    }
    int cnt = min(64, end - base);
    for (int j = 0; j < cnt; j++) {
      float wj = __shfl(w, j);
      if (wj != 0.f) {
        int sj = __shfl(s, j);
        uint4 hv = *(const uint4*)(h + (size_t)sj * DIM + lane * 8);
        u32 hw[4] = {hv.x, hv.y, hv.z, hv.w};
#pragma unroll
        for (int p = 0; p < 4; p++) {
          acc[2 * p]     += wj * bf2f(hw[p] & 0xffffu);
          acc[2 * p + 1] += wj * bf2f(hw[p] >> 16);
        }
      }
    }
  }
  float4 b0 = *(const float4*)(bias + lane * 8);
  float4 b1 = *(const float4*)(bias + lane * 8 + 4);
  float bb[8] = {b0.x, b0.y, b0.z, b0.w, b1.x, b1.y, b1.z, b1.w};
  float* op = oa + (size_t)node * DIM + lane * 8;
#pragma unroll
  for (int t = 0; t < 8; t++) op[t] = acc[t] + bb[t];
}

// ------------------- K8: column sums + total sum of squares ----------------
__global__ __launch_bounds__(256) void k_colstats(const float* __restrict__ oa,
                                                  float* __restrict__ colsum,
                                                  double* __restrict__ ssq) {
  int t = threadIdx.x;
  int r0 = blockIdx.x * 128;
  int r1 = min(r0 + 128, N_NODES);
  float c0 = 0.f, c1 = 0.f, ss = 0.f;
  for (int r = r0; r < r1; r++) {
    float2 v = *(const float2*)(oa + (size_t)r * DIM + 2 * t);
    c0 += v.x; c1 += v.y;
    ss += v.x * v.x + v.y * v.y;
  }
  atomicAdd(&colsum[2 * t], c0);
  atomicAdd(&colsum[2 * t + 1], c1);
#pragma unroll
  for (int d = 1; d < 64; d <<= 1) ss += __shfl_xor(ss, d);
  __shared__ float wss[4];
  int lane = t & 63, wid = t >> 6;
  if (lane == 0) wss[wid] = ss;
  __syncthreads();
  if (t == 0) atomicAdd(ssq, (double)(wss[0] + wss[1] + wss[2] + wss[3]));
}

// --------------------------- K9: finalize scalars --------------------------
__global__ __launch_bounds__(512) void k_finalize(const float* __restrict__ colsum,
                                                  const double* __restrict__ ssq,
                                                  float* __restrict__ mu,
                                                  float* __restrict__ invp) {
  __shared__ double sred[8];
  int j = threadIdx.x;
  float m = colsum[j] * (1.0f / 30000.0f);
  mu[j] = m;
  double p = (double)m * (double)m;
#pragma unroll
  for (int d = 1; d < 64; d <<= 1) p += __shfl_xor(p, d);
  int lane = j & 63, wid = j >> 6;
  if (lane == 0) sred[wid] = p;
  __syncthreads();
  if (j == 0) {
    double smu2 = 0.0;
#pragma unroll
    for (int w = 0; w < 8; w++) smu2 += sred[w];
    double centered = ssq[0] - 30000.0 * smu2;   // sum (x-mu)^2
    double mean = centered * (1.0 / 30000.0);
    if (!(mean >= 0.0)) mean = 0.0;              // guard
    float rn = sqrtf(1e-6f + (float)mean);
    invp[0] = 1.0f / rn;
  }
}

// --------------------- K10: sentinel (diagnostic marker) -------------------
__global__ __launch_bounds__(256) void k_sentinel(float* __restrict__ out) {
  size_t gid = (size_t)blockIdx.x * 256 + threadIdx.x;
  size_t i0 = gid * 4;
  if (i0 >= (size_t)N_NODES * DIM) return;
  *(float4*)(out + i0) = make_float4(0.25f, 0.25f, 0.25f, 0.25f);
}

// ----------------------- K11: center, scale, relu (fp32) -------------------
__global__ __launch_bounds__(256) void k_finalout(const float* __restrict__ oa,
                                                  const float* __restrict__ mu,
                                                  const float* __restrict__ invp,
                                                  float* __restrict__ out) {
  size_t gid = (size_t)blockIdx.x * 256 + threadIdx.x;
  size_t i0 = gid * 4;
  if (i0 >= (size_t)N_NODES * DIM) return;
  float inv = invp[0];
  int j = (int)(i0 & (DIM - 1));
  float4 v = *(const float4*)(oa + i0);
  float4 m = *(const float4*)(mu + j);
  float4 o;
  o.x = (v.x - m.x) * inv; o.x = (o.x < 0.f) ? 0.f : o.x;  // NaN-preserving
  o.y = (v.y - m.y) * inv; o.y = (o.y < 0.f) ? 0.f : o.y;
  o.z = (v.z - m.z) * inv; o.z = (o.z < 0.f) ? 0.f : o.z;
  o.w = (v.w - m.w) * inv; o.w = (o.w < 0.f) ? 0.f : o.w;
  *(float4*)(out + i0) = o;
}

// ---------------------------------------------------------------------------
extern "C" void kernel_launch(void* const* d_in, const int* in_sizes, int n_in,
                              void* d_out, int out_size, void* d_ws, size_t ws_size,
                              hipStream_t stream) {
  const float* x    = (const float*)d_in[0];
  const int*   ei   = (const int*)d_in[1];
  const float* W    = (const float*)d_in[2];
  const float* atts = (const float*)d_in[3];
  const float* attd = (const float*)d_in[4];
  const float* bias = (const float*)d_in[5];
  float* out = (float*)d_out;
  char* ws = (char*)d_ws;

  // layout (94.7 MB): oa fp32 [0, 61.44M); xd bf16 overlays oa (dead after
  // GEMM, oa written later by k_aggregate); h bf16 follows.
  float* oa     = (float*)(ws + 0);            // 61,440,000
  u16*   xd     = (u16*)(ws + 0);              // 30,801,920 (overlay)
  u16*   h      = (u16*)(ws + 61440000);       // 30,801,920
  u16*   Wt     = (u16*)(ws + 92241920);       //    524,288
  float* a_s    = (float*)(ws + 92766208);
  float* a_d    = (float*)(ws + 92886272);
  int*   counts = (int*)(ws + 93006336);
  int*   offs   = (int*)(ws + 93126400);
  int*   cursor = (int*)(ws + 93246464);
  int*   perm   = (int*)(ws + 93366528);       //  1,320,000
  float* colsum = (float*)(ws + 94686528);
  float* mu     = (float*)(ws + 94688576);
  double* ssq   = (double*)(ws + 94690624);
  float* invp   = (float*)(ws + 94690688);     // end 94,690,752

  // JAX key(42) -> partitionable split: k_i = threefry((0,42),(0,i))
  u32 kf0, kf1, ka0, ka1;
  threefry2x32(0u, 42u, 0u, 0u, kf0, kf1);
  threefry2x32(0u, 42u, 0u, 1u, ka0, ka1);

  hipMemsetAsync(counts, 0, 120064, stream);
  hipMemsetAsync((void*)colsum, 0, 4224, stream);

  k_sentinel<<<15000, 256, 0, stream>>>(out);
  k_cvtW<<<256, 256, 0, stream>>>(W, Wt);
  k_dropout<<<7520, 256, 0, stream>>>(x, xd, kf0, kf1);
  k_gemm<<<940, 256, 0, stream>>>(xd, Wt, h);
  k_rowdots<<<7500, 256, 0, stream>>>(h, atts, attd, a_s, a_d);
  k_hist<<<1290, 256, 0, stream>>>(ei, counts);
  k_scan<<<1, 1024, 0, stream>>>(counts, offs, cursor);
  k_scatter<<<1290, 256, 0, stream>>>(ei, cursor, perm);
  k_aggregate<<<7500, 256, 0, stream>>>(ei, offs, perm, a_s, a_d, h, bias, oa, ka0, ka1);
  k_colstats<<<235, 256, 0, stream>>>(oa, colsum, ssq);
  k_finalize<<<1, 512, 0, stream>>>(colsum, ssq, mu, invp);
  k_finalout<<<15000, 256, 0, stream>>>(oa, mu, invp, out);
}

// Round 5
// 341.974 us; speedup vs baseline: 1.0109x; 1.0109x over previous
//
#include <hip/hip_runtime.h>
#include <stdint.h>
#include <math.h>

// ---------------------------------------------------------------------------
// GAT + PairNorm + ReLU, MI355X (gfx950).  Round 5 = Round 4 resubmitted
// (R4 bench died with a Trio-nursery infra error before running).
// Changes vs R3 (345.7 us, absmax 3.9e-3):
//  * k_colstats: 235 -> 938 blocks (32 rows/block). Was top dispatch, 43 us
//    at 8.3% occupancy (latency-bound undersubscription).
//  * k_sentinel removed (k_finalout covers all 15.36M outputs).
//  * k_aggregate: single-gather fast path for deg<=64 (P(deg>64) ~ 1e-30);
//    drops 2 of 3 random-gather passes over perm/ei/a_s.
// Pipeline: fp32 in -> bf16 (dropout folded) -> MFMA GEMM -> bf16 h ->
// fp32 attention/aggregate/PairNorm -> fp32 out.
// RNG: JAX partitionable threefry (fold-like split; bits = o0^o1).
// ---------------------------------------------------------------------------

#define N_NODES 30000
#define MPAD    30080
#define DIM     512
#define NEDGE   300000
#define ETOT    330000

typedef unsigned int u32;
typedef unsigned short u16;

typedef __attribute__((ext_vector_type(8))) short bf16x8;
typedef __attribute__((ext_vector_type(4))) float f32x4;

// ----------------------------- threefry2x32 --------------------------------
__host__ __device__ __forceinline__ void threefry2x32(u32 k0, u32 k1, u32 x0, u32 x1,
                                                      u32& o0, u32& o1) {
  u32 ks2 = k0 ^ k1 ^ 0x1BD11BDAu;
#define TF_R(r) { x0 += x1; x1 = (x1 << r) | (x1 >> (32 - r)); x1 ^= x0; }
  x0 += k0; x1 += k1;
  TF_R(13) TF_R(15) TF_R(26) TF_R(6)
  x0 += k1; x1 += ks2 + 1u;
  TF_R(17) TF_R(29) TF_R(16) TF_R(24)
  x0 += ks2; x1 += k0 + 2u;
  TF_R(13) TF_R(15) TF_R(26) TF_R(6)
  x0 += k0; x1 += k1 + 3u;
  TF_R(17) TF_R(29) TF_R(16) TF_R(24)
  x0 += k1; x1 += ks2 + 4u;
  TF_R(13) TF_R(15) TF_R(26) TF_R(6)
  x0 += ks2; x1 += k0 + 5u;
#undef TF_R
  o0 = x0; o1 = x1;
}

__device__ __forceinline__ u32 tf_fold(u32 k0, u32 k1, u32 idx) {
  u32 a, b;
  threefry2x32(k0, k1, 0u, idx, a, b);
  return a ^ b;
}

__device__ __forceinline__ float bf2f(u32 bits16) {
  return __uint_as_float(bits16 << 16);
}
__device__ __forceinline__ u16 f2bf(float f) {   // RNE
  u32 u = __float_as_uint(f);
  return (u16)((u + 0x7fffu + ((u >> 16) & 1u)) >> 16);
}

// ------------------- K0: W (fp32) -> Wt (bf16, transposed) -----------------
__global__ __launch_bounds__(256) void k_cvtW(const float* __restrict__ W,
                                              u16* __restrict__ Wt) {
  __shared__ u16 tile[32][33];
  int b = blockIdx.x;
  int bk = (b & 15) * 32, bn = (b >> 4) * 32;
  int c = threadIdx.x & 31, r = threadIdx.x >> 5;
#pragma unroll
  for (int rr = 0; rr < 32; rr += 8)
    tile[r + rr][c] = f2bf(W[(size_t)(bk + r + rr) * DIM + bn + c]);
  __syncthreads();
#pragma unroll
  for (int rr = 0; rr < 32; rr += 8)
    Wt[(size_t)(bn + r + rr) * DIM + bk + c] = tile[c][r + rr];
}

// ------------- K1: feature dropout (p=0.5) fp32 -> bf16, pad ---------------
__global__ __launch_bounds__(256) void k_dropout(const float* __restrict__ x,
                                                 u16* __restrict__ xd,
                                                 u32 kf0, u32 kf1) {
  size_t gid = (size_t)blockIdx.x * 256 + threadIdx.x;
  size_t i0 = gid * 8;
  if (i0 >= (size_t)MPAD * DIM) return;
  uint4 o = make_uint4(0u, 0u, 0u, 0u);
  if (i0 < (size_t)N_NODES * DIM) {
    float4 v0 = *(const float4*)(x + i0);
    float4 v1 = *(const float4*)(x + i0 + 4);
    float xv[8] = {v0.x, v0.y, v0.z, v0.w, v1.x, v1.y, v1.z, v1.w};
    u32 res[4];
#pragma unroll
    for (int p = 0; p < 4; p++) {
      u32 b0 = tf_fold(kf0, kf1, (u32)i0 + 2 * p);
      u32 b1 = tf_fold(kf0, kf1, (u32)i0 + 2 * p + 1);
      u32 r0 = (b0 >> 31) ? 0u : (u32)f2bf(2.0f * xv[2 * p]);     // keep <=> u<0.5
      u32 r1 = (b1 >> 31) ? 0u : (u32)f2bf(2.0f * xv[2 * p + 1]);
      res[p] = r0 | (r1 << 16);
    }
    o = make_uint4(res[0], res[1], res[2], res[3]);
  }
  *(uint4*)(xd + i0) = o;
}

// ------------------------------ K2: GEMM -----------------------------------
// h[m][n] = sum_k xd[m][k]*Wt[n][k]. 128x128 tile, 4 waves, 16x16x32 bf16
// MFMA, register->LDS staging.
__global__ __launch_bounds__(256) void k_gemm(const u16* __restrict__ A,
                                              const u16* __restrict__ B,
                                              u16* __restrict__ H) {
  __shared__ __align__(16) u16 lA[128 * 32];
  __shared__ __align__(16) u16 lB[128 * 32];
  const int bn = (blockIdx.x & 3) * 128;
  const int bm = (blockIdx.x >> 2) * 128;
  const int tid = threadIdx.x;
  const int wave = tid >> 6, lane = tid & 63;
  const int quad = lane >> 4, l16 = lane & 15;
  const int wrow = (wave & 1) * 64, wcol = (wave >> 1) * 64;

  f32x4 acc[4][4] = {};
  const int srow = tid >> 2;
  const int scq  = (tid & 3) * 8;

  for (int k0 = 0; k0 < DIM; k0 += 32) {
    uint4 va0 = *(const uint4*)(A + (size_t)(bm + srow) * DIM + k0 + scq);
    uint4 va1 = *(const uint4*)(A + (size_t)(bm + 64 + srow) * DIM + k0 + scq);
    uint4 vb0 = *(const uint4*)(B + (size_t)(bn + srow) * DIM + k0 + scq);
    uint4 vb1 = *(const uint4*)(B + (size_t)(bn + 64 + srow) * DIM + k0 + scq);
    __syncthreads();
    *(uint4*)(lA + srow * 32 + scq) = va0;
    *(uint4*)(lA + (64 + srow) * 32 + scq) = va1;
    *(uint4*)(lB + srow * 32 + scq) = vb0;
    *(uint4*)(lB + (64 + srow) * 32 + scq) = vb1;
    __syncthreads();

    bf16x8 af[4], bfr[4];
#pragma unroll
    for (int i = 0; i < 4; i++)
      af[i] = *(const bf16x8*)(lA + (wrow + i * 16 + l16) * 32 + quad * 8);
#pragma unroll
    for (int j = 0; j < 4; j++)
      bfr[j] = *(const bf16x8*)(lB + (wcol + j * 16 + l16) * 32 + quad * 8);
#pragma unroll
    for (int i = 0; i < 4; i++)
#pragma unroll
      for (int j = 0; j < 4; j++)
        acc[i][j] = __builtin_amdgcn_mfma_f32_16x16x32_bf16(af[i], bfr[j], acc[i][j], 0, 0, 0);
  }
#pragma unroll
  for (int i = 0; i < 4; i++) {
#pragma unroll
    for (int r = 0; r < 4; r++) {
      int row = bm + wrow + i * 16 + quad * 4 + r;
      u16* hp = H + (size_t)row * DIM + bn + wcol + l16;
#pragma unroll
      for (int j = 0; j < 4; j++) hp[j * 16] = f2bf(acc[i][j][r]);
    }
  }
}

// ---------------- K3: per-row attention dots a_s, a_d ----------------------
__global__ __launch_bounds__(256) void k_rowdots(const u16* __restrict__ h,
                                                 const float* __restrict__ atts,
                                                 const float* __restrict__ attd,
                                                 float* __restrict__ a_s,
                                                 float* __restrict__ a_d) {
  int row = blockIdx.x * 4 + (threadIdx.x >> 6);
  if (row >= N_NODES) return;
  int lane = threadIdx.x & 63;
  uint4 hv = *(const uint4*)(h + (size_t)row * DIM + lane * 8);
  float4 s0 = *(const float4*)(atts + lane * 8);
  float4 s1 = *(const float4*)(atts + lane * 8 + 4);
  float4 d0 = *(const float4*)(attd + lane * 8);
  float4 d1 = *(const float4*)(attd + lane * 8 + 4);
  u32 hw[4] = {hv.x, hv.y, hv.z, hv.w};
  float sa[8] = {s0.x, s0.y, s0.z, s0.w, s1.x, s1.y, s1.z, s1.w};
  float da[8] = {d0.x, d0.y, d0.z, d0.w, d1.x, d1.y, d1.z, d1.w};
  float ps = 0.f, pd = 0.f;
#pragma unroll
  for (int p = 0; p < 4; p++) {
    float h0 = bf2f(hw[p] & 0xffffu), h1 = bf2f(hw[p] >> 16);
    ps += h0 * sa[2 * p] + h1 * sa[2 * p + 1];
    pd += h0 * da[2 * p] + h1 * da[2 * p + 1];
  }
#pragma unroll
  for (int d = 1; d < 64; d <<= 1) { ps += __shfl_xor(ps, d); pd += __shfl_xor(pd, d); }
  if (lane == 0) { a_s[row] = ps; a_d[row] = pd; }
}

// -------------------- K4/K5/K6: counting sort by dst -----------------------
__global__ __launch_bounds__(256) void k_hist(const int* __restrict__ ei,
                                              int* __restrict__ counts) {
  int i = blockIdx.x * 256 + threadIdx.x;
  if (i >= ETOT) return;
  int d = (i < NEDGE) ? ei[NEDGE + i] : (i - NEDGE);
  atomicAdd(&counts[d], 1);
}

__global__ __launch_bounds__(1024) void k_scan(const int* __restrict__ counts,
                                               int* __restrict__ off,
                                               int* __restrict__ cursor) {
  __shared__ int wsum[16];
  __shared__ int s_total;
  int tid = threadIdx.x, lane = tid & 63, wid = tid >> 6;
  int carry = 0;
  for (int base = 0; base < N_NODES; base += 1024) {
    int i = base + tid;
    int v = (i < N_NODES) ? counts[i] : 0;
    int x = v;
#pragma unroll
    for (int d = 1; d < 64; d <<= 1) {
      int y = __shfl_up(x, d);
      if (lane >= d) x += y;
    }
    if (lane == 63) wsum[wid] = x;
    __syncthreads();
    if (tid == 0) {
      int run = 0;
#pragma unroll
      for (int w = 0; w < 16; w++) { int tv = wsum[w]; wsum[w] = run; run += tv; }
      s_total = run;
    }
    __syncthreads();
    int excl = x - v + wsum[wid] + carry;
    if (i < N_NODES) { off[i] = excl; cursor[i] = excl; }
    carry += s_total;
    __syncthreads();
  }
  if (tid == 0) off[N_NODES] = carry;
}

__global__ __launch_bounds__(256) void k_scatter(const int* __restrict__ ei,
                                                 int* __restrict__ cursor,
                                                 int* __restrict__ perm) {
  int i = blockIdx.x * 256 + threadIdx.x;
  if (i >= ETOT) return;
  int d = (i < NEDGE) ? ei[NEDGE + i] : (i - NEDGE);
  int slot = atomicAdd(&cursor[d], 1);
  perm[slot] = i;
}

// -------- K7: segment softmax + attention dropout + aggregation ------------
// One wave per dst node; lane j owns cols [8j,8j+8).
// Fast path (deg<=64, ~always): single gather pass, logit kept in-register.
__global__ __launch_bounds__(256) void k_aggregate(
    const int* __restrict__ ei, const int* __restrict__ off, const int* __restrict__ perm,
    const float* __restrict__ a_s, const float* __restrict__ a_d,
    const u16* __restrict__ h, const float* __restrict__ bias,
    float* __restrict__ oa, u32 ka0, u32 ka1) {
  int node = blockIdx.x * 4 + (threadIdx.x >> 6);
  if (node >= N_NODES) return;
  int lane = threadIdx.x & 63;
  int beg = off[node], end = off[node + 1];
  int deg = end - beg;
  float adn = a_d[node];

  float acc[8] = {0.f, 0.f, 0.f, 0.f, 0.f, 0.f, 0.f, 0.f};

  if (deg <= 64) {
    // ---- fast path: one gather, everything in registers ----
    int idx = beg + lane;
    bool valid = idx < end;
    int s = 0;
    float lg = -3.0e38f;
    u32 keepbits = 0;
    if (valid) {
      int eid = perm[idx];
      s = (eid < NEDGE) ? ei[eid] : (eid - NEDGE);
      lg = a_s[s] + adn;
      lg = (lg < 0.f) ? 0.2f * lg : lg;
      keepbits = tf_fold(ka0, ka1, (u32)eid);
    }
    float mx = lg;
#pragma unroll
    for (int d = 1; d < 64; d <<= 1) mx = fmaxf(mx, __shfl_xor(mx, d));
    float ee = valid ? expf(lg - mx) : 0.f;
    float ssum = ee;
#pragma unroll
    for (int d = 1; d < 64; d <<= 1) ssum += __shfl_xor(ssum, d);
    float inv_s = 2.5f / (ssum + 1e-16f);   // folds 1/(1-0.6) dropout scale
    float w = (valid && ((keepbits >> 9) < 3355444u)) ? ee * inv_s : 0.f;

    for (int j = 0; j < deg; j++) {
      float wj = __shfl(w, j);
      if (wj != 0.f) {
        int sj = __shfl(s, j);
        uint4 hv = *(const uint4*)(h + (size_t)sj * DIM + lane * 8);
        u32 hw[4] = {hv.x, hv.y, hv.z, hv.w};
#pragma unroll
        for (int p = 0; p < 4; p++) {
          acc[2 * p]     += wj * bf2f(hw[p] & 0xffffu);
          acc[2 * p + 1] += wj * bf2f(hw[p] >> 16);
        }
      }
    }
  } else {
    // ---- fallback (deg>64): 3-pass loop ----
    float mx = -3.0e38f;
    for (int base = beg; base < end; base += 64) {
      int idx = base + lane;
      if (idx < end) {
        int eid = perm[idx];
        int s = (eid < NEDGE) ? ei[eid] : (eid - NEDGE);
        float lg = a_s[s] + adn;
        lg = (lg < 0.f) ? 0.2f * lg : lg;
        mx = fmaxf(mx, lg);
      }
    }
#pragma unroll
    for (int d = 1; d < 64; d <<= 1) mx = fmaxf(mx, __shfl_xor(mx, d));
    float ssum = 0.f;
    for (int base = beg; base < end; base += 64) {
      int idx = base + lane;
      if (idx < end) {
        int eid = perm[idx];
        int s = (eid < NEDGE) ? ei[eid] : (eid - NEDGE);
        float lg = a_s[s] + adn;
        lg = (lg < 0.f) ? 0.2f * lg : lg;
        ssum += expf(lg - mx);
      }
    }
#pragma unroll
    for (int d = 1; d < 64; d <<= 1) ssum += __shfl_xor(ssum, d);
    float inv_s = 2.5f / (ssum + 1e-16f);
    for (int base = beg; base < end; base += 64) {
      int idx = base + lane;
      float w = 0.f; int s = 0;
      if (idx < end) {
        int eid = perm[idx];
        s = (eid < NEDGE) ? ei[eid] : (eid - NEDGE);
        float lg = a_s[s] + adn;
        lg = (lg < 0.f) ? 0.2f * lg : lg;
        float ee = expf(lg - mx);
        u32 bits = tf_fold(ka0, ka1, (u32)eid);
        if ((bits >> 9) < 3355444u) w = ee * inv_s;
      }
      int cnt = min(64, end - base);
      for (int j = 0; j < cnt; j++) {
        float wj = __shfl(w, j);
        if (wj != 0.f) {
          int sj = __shfl(s, j);
          uint4 hv = *(const uint4*)(h + (size_t)sj * DIM + lane * 8);
          u32 hw[4] = {hv.x, hv.y, hv.z, hv.w};
#pragma unroll
          for (int p = 0; p < 4; p++) {
            acc[2 * p]     += wj * bf2f(hw[p] & 0xffffu);
            acc[2 * p + 1] += wj * bf2f(hw[p] >> 16);
          }
        }
      }
    }
  }

  float4 b0 = *(const float4*)(bias + lane * 8);
  float4 b1 = *(const float4*)(bias + lane * 8 + 4);
  float bb[8] = {b0.x, b0.y, b0.z, b0.w, b1.x, b1.y, b1.z, b1.w};
  float* op = oa + (size_t)node * DIM + lane * 8;
#pragma unroll
  for (int t = 0; t < 8; t++) op[t] = acc[t] + bb[t];
}

// ------------------- K8: column sums + total sum of squares ----------------
// 32 rows/block -> 938 blocks (R3: 235 blocks was 8.3% occupancy, 43 us).
#define CS_ROWS 32
__global__ __launch_bounds__(256) void k_colstats(const float* __restrict__ oa,
                                                  float* __restrict__ colsum,
                                                  double* __restrict__ ssq) {
  int t = threadIdx.x;
  int r0 = blockIdx.x * CS_ROWS;
  int r1 = min(r0 + CS_ROWS, N_NODES);
  float c0 = 0.f, c1 = 0.f, ss = 0.f;
  for (int r = r0; r < r1; r++) {
    float2 v = *(const float2*)(oa + (size_t)r * DIM + 2 * t);
    c0 += v.x; c1 += v.y;
    ss += v.x * v.x + v.y * v.y;
  }
  atomicAdd(&colsum[2 * t], c0);
  atomicAdd(&colsum[2 * t + 1], c1);
#pragma unroll
  for (int d = 1; d < 64; d <<= 1) ss += __shfl_xor(ss, d);
  __shared__ float wss[4];
  int lane = t & 63, wid = t >> 6;
  if (lane == 0) wss[wid] = ss;
  __syncthreads();
  if (t == 0) atomicAdd(ssq, (double)(wss[0] + wss[1] + wss[2] + wss[3]));
}

// --------------------------- K9: finalize scalars --------------------------
__global__ __launch_bounds__(512) void k_finalize(const float* __restrict__ colsum,
                                                  const double* __restrict__ ssq,
                                                  float* __restrict__ mu,
                                                  float* __restrict__ invp) {
  __shared__ double sred[8];
  int j = threadIdx.x;
  float m = colsum[j] * (1.0f / 30000.0f);
  mu[j] = m;
  double p = (double)m * (double)m;
#pragma unroll
  for (int d = 1; d < 64; d <<= 1) p += __shfl_xor(p, d);
  int lane = j & 63, wid = j >> 6;
  if (lane == 0) sred[wid] = p;
  __syncthreads();
  if (j == 0) {
    double smu2 = 0.0;
#pragma unroll
    for (int w = 0; w < 8; w++) smu2 += sred[w];
    double centered = ssq[0] - 30000.0 * smu2;   // sum (x-mu)^2
    double mean = centered * (1.0 / 30000.0);
    if (!(mean >= 0.0)) mean = 0.0;              // guard
    float rn = sqrtf(1e-6f + (float)mean);
    invp[0] = 1.0f / rn;
  }
}

// ----------------------- K10: center, scale, relu (fp32) -------------------
__global__ __launch_bounds__(256) void k_finalout(const float* __restrict__ oa,
                                                  const float* __restrict__ mu,
                                                  const float* __restrict__ invp,
                                                  float* __restrict__ out) {
  size_t gid = (size_t)blockIdx.x * 256 + threadIdx.x;
  size_t i0 = gid * 4;
  if (i0 >= (size_t)N_NODES * DIM) return;
  float inv = invp[0];
  int j = (int)(i0 & (DIM - 1));
  float4 v = *(const float4*)(oa + i0);
  float4 m = *(const float4*)(mu + j);
  float4 o;
  o.x = (v.x - m.x) * inv; o.x = (o.x < 0.f) ? 0.f : o.x;
  o.y = (v.y - m.y) * inv; o.y = (o.y < 0.f) ? 0.f : o.y;
  o.z = (v.z - m.z) * inv; o.z = (o.z < 0.f) ? 0.f : o.z;
  o.w = (v.w - m.w) * inv; o.w = (o.w < 0.f) ? 0.f : o.w;
  *(float4*)(out + i0) = o;
}

// ---------------------------------------------------------------------------
extern "C" void kernel_launch(void* const* d_in, const int* in_sizes, int n_in,
                              void* d_out, int out_size, void* d_ws, size_t ws_size,
                              hipStream_t stream) {
  const float* x    = (const float*)d_in[0];
  const int*   ei   = (const int*)d_in[1];
  const float* W    = (const float*)d_in[2];
  const float* atts = (const float*)d_in[3];
  const float* attd = (const float*)d_in[4];
  const float* bias = (const float*)d_in[5];
  float* out = (float*)d_out;
  char* ws = (char*)d_ws;

  float* oa     = (float*)(ws + 0);            // 61,440,000
  u16*   xd     = (u16*)(ws + 0);              // 30,801,920 (overlay, dead after GEMM)
  u16*   h      = (u16*)(ws + 61440000);       // 30,801,920
  u16*   Wt     = (u16*)(ws + 92241920);       //    524,288
  float* a_s    = (float*)(ws + 92766208);
  float* a_d    = (float*)(ws + 92886272);
  int*   counts = (int*)(ws + 93006336);
  int*   offs   = (int*)(ws + 93126400);
  int*   cursor = (int*)(ws + 93246464);
  int*   perm   = (int*)(ws + 93366528);       //  1,320,000
  float* colsum = (float*)(ws + 94686528);
  float* mu     = (float*)(ws + 94688576);
  double* ssq   = (double*)(ws + 94690624);
  float* invp   = (float*)(ws + 94690688);     // end 94,690,752

  u32 kf0, kf1, ka0, ka1;
  threefry2x32(0u, 42u, 0u, 0u, kf0, kf1);
  threefry2x32(0u, 42u, 0u, 1u, ka0, ka1);

  hipMemsetAsync(counts, 0, 120064, stream);
  hipMemsetAsync((void*)colsum, 0, 4224, stream);

  k_cvtW<<<256, 256, 0, stream>>>(W, Wt);
  k_dropout<<<7520, 256, 0, stream>>>(x, xd, kf0, kf1);
  k_gemm<<<940, 256, 0, stream>>>(xd, Wt, h);
  k_rowdots<<<7500, 256, 0, stream>>>(h, atts, attd, a_s, a_d);
  k_hist<<<1290, 256, 0, stream>>>(ei, counts);
  k_scan<<<1, 1024, 0, stream>>>(counts, offs, cursor);
  k_scatter<<<1290, 256, 0, stream>>>(ei, cursor, perm);
  k_aggregate<<<7500, 256, 0, stream>>>(ei, offs, perm, a_s, a_d, h, bias, oa, ka0, ka1);
  k_colstats<<<(N_NODES + CS_ROWS - 1) / CS_ROWS, 256, 0, stream>>>(oa, colsum, ssq);
  k_finalize<<<1, 512, 0, stream>>>(colsum, ssq, mu, invp);
  k_finalout<<<15000, 256, 0, stream>>>(oa, mu, invp, out);
}

// Round 6
// 304.299 us; speedup vs baseline: 1.1360x; 1.1238x over previous
//
#include <hip/hip_runtime.h>
#include <stdint.h>
#include <math.h>

// ---------------------------------------------------------------------------
// GAT + PairNorm + ReLU, MI355X (gfx950).  Round 6.
// R5 post-mortem: k_colstats regressed 43->56.5us; WRITE_SIZE 4x = global
// fp32 atomic RMW chains (938 deep per colsum address). Fix is structural:
//  * k_colstats DELETED. Column partials + ssq partials are computed in
//    k_aggregate's epilogue via an 8KB LDS block transpose (no atomics),
//    written per-block to d_out (dead until k_finalout -> free scratch).
//  * k_redstats: 60 blocks reduce 7500 partial rows; 60-deep atomics only.
// Pipeline: fp32 in -> bf16 (dropout folded) -> MFMA GEMM -> bf16 h ->
// fp32 attention/aggregate(+stats) -> PairNorm -> fp32 out.
// RNG: JAX partitionable threefry (fold-like split; bits = o0^o1).
// ---------------------------------------------------------------------------

#define N_NODES 30000
#define MPAD    30080
#define DIM     512
#define NEDGE   300000
#define ETOT    330000
#define AGG_BLOCKS 7500          // 4 nodes/block, exactly 30000 nodes
#define RED_BLOCKS 60            // 7500 = 60 * 125
#define RED_ROWS   125

typedef unsigned int u32;
typedef unsigned short u16;

typedef __attribute__((ext_vector_type(8))) short bf16x8;
typedef __attribute__((ext_vector_type(4))) float f32x4;

// ----------------------------- threefry2x32 --------------------------------
__host__ __device__ __forceinline__ void threefry2x32(u32 k0, u32 k1, u32 x0, u32 x1,
                                                      u32& o0, u32& o1) {
  u32 ks2 = k0 ^ k1 ^ 0x1BD11BDAu;
#define TF_R(r) { x0 += x1; x1 = (x1 << r) | (x1 >> (32 - r)); x1 ^= x0; }
  x0 += k0; x1 += k1;
  TF_R(13) TF_R(15) TF_R(26) TF_R(6)
  x0 += k1; x1 += ks2 + 1u;
  TF_R(17) TF_R(29) TF_R(16) TF_R(24)
  x0 += ks2; x1 += k0 + 2u;
  TF_R(13) TF_R(15) TF_R(26) TF_R(6)
  x0 += k0; x1 += k1 + 3u;
  TF_R(17) TF_R(29) TF_R(16) TF_R(24)
  x0 += k1; x1 += ks2 + 4u;
  TF_R(13) TF_R(15) TF_R(26) TF_R(6)
  x0 += ks2; x1 += k0 + 5u;
#undef TF_R
  o0 = x0; o1 = x1;
}

__device__ __forceinline__ u32 tf_fold(u32 k0, u32 k1, u32 idx) {
  u32 a, b;
  threefry2x32(k0, k1, 0u, idx, a, b);
  return a ^ b;
}

__device__ __forceinline__ float bf2f(u32 bits16) {
  return __uint_as_float(bits16 << 16);
}
__device__ __forceinline__ u16 f2bf(float f) {   // RNE
  u32 u = __float_as_uint(f);
  return (u16)((u + 0x7fffu + ((u >> 16) & 1u)) >> 16);
}

// ------------------- K0: W (fp32) -> Wt (bf16, transposed) -----------------
__global__ __launch_bounds__(256) void k_cvtW(const float* __restrict__ W,
                                              u16* __restrict__ Wt) {
  __shared__ u16 tile[32][33];
  int b = blockIdx.x;
  int bk = (b & 15) * 32, bn = (b >> 4) * 32;
  int c = threadIdx.x & 31, r = threadIdx.x >> 5;
#pragma unroll
  for (int rr = 0; rr < 32; rr += 8)
    tile[r + rr][c] = f2bf(W[(size_t)(bk + r + rr) * DIM + bn + c]);
  __syncthreads();
#pragma unroll
  for (int rr = 0; rr < 32; rr += 8)
    Wt[(size_t)(bn + r + rr) * DIM + bk + c] = tile[c][r + rr];
}

// ------------- K1: feature dropout (p=0.5) fp32 -> bf16, pad ---------------
__global__ __launch_bounds__(256) void k_dropout(const float* __restrict__ x,
                                                 u16* __restrict__ xd,
                                                 u32 kf0, u32 kf1) {
  size_t gid = (size_t)blockIdx.x * 256 + threadIdx.x;
  size_t i0 = gid * 8;
  if (i0 >= (size_t)MPAD * DIM) return;
  uint4 o = make_uint4(0u, 0u, 0u, 0u);
  if (i0 < (size_t)N_NODES * DIM) {
    float4 v0 = *(const float4*)(x + i0);
    float4 v1 = *(const float4*)(x + i0 + 4);
    float xv[8] = {v0.x, v0.y, v0.z, v0.w, v1.x, v1.y, v1.z, v1.w};
    u32 res[4];
#pragma unroll
    for (int p = 0; p < 4; p++) {
      u32 b0 = tf_fold(kf0, kf1, (u32)i0 + 2 * p);
      u32 b1 = tf_fold(kf0, kf1, (u32)i0 + 2 * p + 1);
      u32 r0 = (b0 >> 31) ? 0u : (u32)f2bf(2.0f * xv[2 * p]);     // keep <=> u<0.5
      u32 r1 = (b1 >> 31) ? 0u : (u32)f2bf(2.0f * xv[2 * p + 1]);
      res[p] = r0 | (r1 << 16);
    }
    o = make_uint4(res[0], res[1], res[2], res[3]);
  }
  *(uint4*)(xd + i0) = o;
}

// ------------------------------ K2: GEMM -----------------------------------
__global__ __launch_bounds__(256) void k_gemm(const u16* __restrict__ A,
                                              const u16* __restrict__ B,
                                              u16* __restrict__ H) {
  __shared__ __align__(16) u16 lA[128 * 32];
  __shared__ __align__(16) u16 lB[128 * 32];
  const int bn = (blockIdx.x & 3) * 128;
  const int bm = (blockIdx.x >> 2) * 128;
  const int tid = threadIdx.x;
  const int wave = tid >> 6, lane = tid & 63;
  const int quad = lane >> 4, l16 = lane & 15;
  const int wrow = (wave & 1) * 64, wcol = (wave >> 1) * 64;

  f32x4 acc[4][4] = {};
  const int srow = tid >> 2;
  const int scq  = (tid & 3) * 8;

  for (int k0 = 0; k0 < DIM; k0 += 32) {
    uint4 va0 = *(const uint4*)(A + (size_t)(bm + srow) * DIM + k0 + scq);
    uint4 va1 = *(const uint4*)(A + (size_t)(bm + 64 + srow) * DIM + k0 + scq);
    uint4 vb0 = *(const uint4*)(B + (size_t)(bn + srow) * DIM + k0 + scq);
    uint4 vb1 = *(const uint4*)(B + (size_t)(bn + 64 + srow) * DIM + k0 + scq);
    __syncthreads();
    *(uint4*)(lA + srow * 32 + scq) = va0;
    *(uint4*)(lA + (64 + srow) * 32 + scq) = va1;
    *(uint4*)(lB + srow * 32 + scq) = vb0;
    *(uint4*)(lB + (64 + srow) * 32 + scq) = vb1;
    __syncthreads();

    bf16x8 af[4], bfr[4];
#pragma unroll
    for (int i = 0; i < 4; i++)
      af[i] = *(const bf16x8*)(lA + (wrow + i * 16 + l16) * 32 + quad * 8);
#pragma unroll
    for (int j = 0; j < 4; j++)
      bfr[j] = *(const bf16x8*)(lB + (wcol + j * 16 + l16) * 32 + quad * 8);
#pragma unroll
    for (int i = 0; i < 4; i++)
#pragma unroll
      for (int j = 0; j < 4; j++)
        acc[i][j] = __builtin_amdgcn_mfma_f32_16x16x32_bf16(af[i], bfr[j], acc[i][j], 0, 0, 0);
  }
#pragma unroll
  for (int i = 0; i < 4; i++) {
#pragma unroll
    for (int r = 0; r < 4; r++) {
      int row = bm + wrow + i * 16 + quad * 4 + r;
      u16* hp = H + (size_t)row * DIM + bn + wcol + l16;
#pragma unroll
      for (int j = 0; j < 4; j++) hp[j * 16] = f2bf(acc[i][j][r]);
    }
  }
}

// ---------------- K3: per-row attention dots a_s, a_d ----------------------
__global__ __launch_bounds__(256) void k_rowdots(const u16* __restrict__ h,
                                                 const float* __restrict__ atts,
                                                 const float* __restrict__ attd,
                                                 float* __restrict__ a_s,
                                                 float* __restrict__ a_d) {
  int row = blockIdx.x * 4 + (threadIdx.x >> 6);
  if (row >= N_NODES) return;
  int lane = threadIdx.x & 63;
  uint4 hv = *(const uint4*)(h + (size_t)row * DIM + lane * 8);
  float4 s0 = *(const float4*)(atts + lane * 8);
  float4 s1 = *(const float4*)(atts + lane * 8 + 4);
  float4 d0 = *(const float4*)(attd + lane * 8);
  float4 d1 = *(const float4*)(attd + lane * 8 + 4);
  u32 hw[4] = {hv.x, hv.y, hv.z, hv.w};
  float sa[8] = {s0.x, s0.y, s0.z, s0.w, s1.x, s1.y, s1.z, s1.w};
  float da[8] = {d0.x, d0.y, d0.z, d0.w, d1.x, d1.y, d1.z, d1.w};
  float ps = 0.f, pd = 0.f;
#pragma unroll
  for (int p = 0; p < 4; p++) {
    float h0 = bf2f(hw[p] & 0xffffu), h1 = bf2f(hw[p] >> 16);
    ps += h0 * sa[2 * p] + h1 * sa[2 * p + 1];
    pd += h0 * da[2 * p] + h1 * da[2 * p + 1];
  }
#pragma unroll
  for (int d = 1; d < 64; d <<= 1) { ps += __shfl_xor(ps, d); pd += __shfl_xor(pd, d); }
  if (lane == 0) { a_s[row] = ps; a_d[row] = pd; }
}

// -------------------- K4/K5/K6: counting sort by dst -----------------------
__global__ __launch_bounds__(256) void k_hist(const int* __restrict__ ei,
                                              int* __restrict__ counts) {
  int i = blockIdx.x * 256 + threadIdx.x;
  if (i >= ETOT) return;
  int d = (i < NEDGE) ? ei[NEDGE + i] : (i - NEDGE);
  atomicAdd(&counts[d], 1);
}

__global__ __launch_bounds__(1024) void k_scan(const int* __restrict__ counts,
                                               int* __restrict__ off,
                                               int* __restrict__ cursor) {
  __shared__ int wsum[16];
  __shared__ int s_total;
  int tid = threadIdx.x, lane = tid & 63, wid = tid >> 6;
  int carry = 0;
  for (int base = 0; base < N_NODES; base += 1024) {
    int i = base + tid;
    int v = (i < N_NODES) ? counts[i] : 0;
    int x = v;
#pragma unroll
    for (int d = 1; d < 64; d <<= 1) {
      int y = __shfl_up(x, d);
      if (lane >= d) x += y;
    }
    if (lane == 63) wsum[wid] = x;
    __syncthreads();
    if (tid == 0) {
      int run = 0;
#pragma unroll
      for (int w = 0; w < 16; w++) { int tv = wsum[w]; wsum[w] = run; run += tv; }
      s_total = run;
    }
    __syncthreads();
    int excl = x - v + wsum[wid] + carry;
    if (i < N_NODES) { off[i] = excl; cursor[i] = excl; }
    carry += s_total;
    __syncthreads();
  }
  if (tid == 0) off[N_NODES] = carry;
}

__global__ __launch_bounds__(256) void k_scatter(const int* __restrict__ ei,
                                                 int* __restrict__ cursor,
                                                 int* __restrict__ perm) {
  int i = blockIdx.x * 256 + threadIdx.x;
  if (i >= ETOT) return;
  int d = (i < NEDGE) ? ei[NEDGE + i] : (i - NEDGE);
  int slot = atomicAdd(&cursor[d], 1);
  perm[slot] = i;
}

// ----- K7: segment softmax + attention dropout + aggregation + stats -------
// One wave per dst node; lane j owns cols [8j,8j+8). Epilogue: block (4
// nodes) writes column partials + ssq partial -> colpart/ssqpart (in d_out).
__global__ __launch_bounds__(256) void k_aggregate(
    const int* __restrict__ ei, const int* __restrict__ off, const int* __restrict__ perm,
    const float* __restrict__ a_s, const float* __restrict__ a_d,
    const u16* __restrict__ h, const float* __restrict__ bias,
    float* __restrict__ oa, float* __restrict__ colpart,
    float* __restrict__ ssqpart, u32 ka0, u32 ka1) {
  __shared__ float lbuf[4][512];
  int wid = threadIdx.x >> 6;
  int node = blockIdx.x * 4 + wid;          // grid exactly covers 30000 nodes
  int lane = threadIdx.x & 63;
  int beg = off[node], end = off[node + 1];
  int deg = end - beg;
  float adn = a_d[node];

  float acc[8] = {0.f, 0.f, 0.f, 0.f, 0.f, 0.f, 0.f, 0.f};

  if (deg <= 64) {
    // ---- fast path: one gather, everything in registers ----
    int idx = beg + lane;
    bool valid = idx < end;
    int s = 0;
    float lg = -3.0e38f;
    u32 keepbits = 0;
    if (valid) {
      int eid = perm[idx];
      s = (eid < NEDGE) ? ei[eid] : (eid - NEDGE);
      lg = a_s[s] + adn;
      lg = (lg < 0.f) ? 0.2f * lg : lg;
      keepbits = tf_fold(ka0, ka1, (u32)eid);
    }
    float mx = lg;
#pragma unroll
    for (int d = 1; d < 64; d <<= 1) mx = fmaxf(mx, __shfl_xor(mx, d));
    float ee = valid ? expf(lg - mx) : 0.f;
    float ssum = ee;
#pragma unroll
    for (int d = 1; d < 64; d <<= 1) ssum += __shfl_xor(ssum, d);
    float inv_s = 2.5f / (ssum + 1e-16f);   // folds 1/(1-0.6) dropout scale
    float w = (valid && ((keepbits >> 9) < 3355444u)) ? ee * inv_s : 0.f;

    for (int j = 0; j < deg; j++) {
      float wj = __shfl(w, j);
      if (wj != 0.f) {
        int sj = __shfl(s, j);
        uint4 hv = *(const uint4*)(h + (size_t)sj * DIM + lane * 8);
        u32 hw[4] = {hv.x, hv.y, hv.z, hv.w};
#pragma unroll
        for (int p = 0; p < 4; p++) {
          acc[2 * p]     += wj * bf2f(hw[p] & 0xffffu);
          acc[2 * p + 1] += wj * bf2f(hw[p] >> 16);
        }
      }
    }
  } else {
    // ---- fallback (deg>64): 3-pass loop ----
    float mx = -3.0e38f;
    for (int base = beg; base < end; base += 64) {
      int idx = base + lane;
      if (idx < end) {
        int eid = perm[idx];
        int s = (eid < NEDGE) ? ei[eid] : (eid - NEDGE);
        float lg = a_s[s] + adn;
        lg = (lg < 0.f) ? 0.2f * lg : lg;
        mx = fmaxf(mx, lg);
      }
    }
#pragma unroll
    for (int d = 1; d < 64; d <<= 1) mx = fmaxf(mx, __shfl_xor(mx, d));
    float ssum = 0.f;
    for (int base = beg; base < end; base += 64) {
      int idx = base + lane;
      if (idx < end) {
        int eid = perm[idx];
        int s = (eid < NEDGE) ? ei[eid] : (eid - NEDGE);
        float lg = a_s[s] + adn;
        lg = (lg < 0.f) ? 0.2f * lg : lg;
        ssum += expf(lg - mx);
      }
    }
#pragma unroll
    for (int d = 1; d < 64; d <<= 1) ssum += __shfl_xor(ssum, d);
    float inv_s = 2.5f / (ssum + 1e-16f);
    for (int base = beg; base < end; base += 64) {
      int idx = base + lane;
      float w = 0.f; int s = 0;
      if (idx < end) {
        int eid = perm[idx];
        s = (eid < NEDGE) ? ei[eid] : (eid - NEDGE);
        float lg = a_s[s] + adn;
        lg = (lg < 0.f) ? 0.2f * lg : lg;
        float ee = expf(lg - mx);
        u32 bits = tf_fold(ka0, ka1, (u32)eid);
        if ((bits >> 9) < 3355444u) w = ee * inv_s;
      }
      int cnt = min(64, end - base);
      for (int j = 0; j < cnt; j++) {
        float wj = __shfl(w, j);
        if (wj != 0.f) {
          int sj = __shfl(s, j);
          uint4 hv = *(const uint4*)(h + (size_t)sj * DIM + lane * 8);
          u32 hw[4] = {hv.x, hv.y, hv.z, hv.w};
#pragma unroll
          for (int p = 0; p < 4; p++) {
            acc[2 * p]     += wj * bf2f(hw[p] & 0xffffu);
            acc[2 * p + 1] += wj * bf2f(hw[p] >> 16);
          }
        }
      }
    }
  }

  // epilogue: add bias, write oa, stash row in LDS for block stats
  float4 b0 = *(const float4*)(bias + lane * 8);
  float4 b1 = *(const float4*)(bias + lane * 8 + 4);
  float bb[8] = {b0.x, b0.y, b0.z, b0.w, b1.x, b1.y, b1.z, b1.w};
  float val[8];
#pragma unroll
  for (int t = 0; t < 8; t++) val[t] = acc[t] + bb[t];
  float* op = oa + (size_t)node * DIM + lane * 8;
#pragma unroll
  for (int t = 0; t < 8; t++) op[t] = val[t];
  *(float4*)&lbuf[wid][lane * 8]     = make_float4(val[0], val[1], val[2], val[3]);
  *(float4*)&lbuf[wid][lane * 8 + 4] = make_float4(val[4], val[5], val[6], val[7]);
  __syncthreads();

  int t = threadIdx.x;                      // 0..255 -> columns t and t+256
  float s0 = 0.f, s1 = 0.f, ssl = 0.f;
#pragma unroll
  for (int w = 0; w < 4; w++) {
    float a = lbuf[w][t], b = lbuf[w][t + 256];
    s0 += a; s1 += b;
    ssl = fmaf(a, a, ssl);
    ssl = fmaf(b, b, ssl);
  }
  colpart[(size_t)blockIdx.x * 512 + t]       = s0;
  colpart[(size_t)blockIdx.x * 512 + 256 + t] = s1;
#pragma unroll
  for (int d = 1; d < 64; d <<= 1) ssl += __shfl_xor(ssl, d);
  __shared__ float wss[4];
  if ((t & 63) == 0) wss[t >> 6] = ssl;
  __syncthreads();
  if (t == 0) ssqpart[blockIdx.x] = wss[0] + wss[1] + wss[2] + wss[3];
}

// ------------- K8: reduce column partials + ssq (depth-60 atomics) ---------
__global__ __launch_bounds__(256) void k_redstats(const float* __restrict__ colpart,
                                                  const float* __restrict__ ssqpart,
                                                  float* __restrict__ colsum,
                                                  double* __restrict__ ssq) {
  int b = blockIdx.x;                       // RED_BLOCKS
  int t = threadIdx.x;
  int r0 = b * RED_ROWS;
  float s0 = 0.f, s1 = 0.f;
  for (int r = r0; r < r0 + RED_ROWS; r++) {
    s0 += colpart[(size_t)r * 512 + t];
    s1 += colpart[(size_t)r * 512 + 256 + t];
  }
  atomicAdd(&colsum[t], s0);
  atomicAdd(&colsum[t + 256], s1);
  float sl = (t < RED_ROWS) ? ssqpart[r0 + t] : 0.f;
#pragma unroll
  for (int d = 1; d < 64; d <<= 1) sl += __shfl_xor(sl, d);
  __shared__ float w4[4];
  if ((t & 63) == 0) w4[t >> 6] = sl;
  __syncthreads();
  if (t == 0) atomicAdd(ssq, (double)(w4[0] + w4[1] + w4[2] + w4[3]));
}

// --------------------------- K9: finalize scalars --------------------------
__global__ __launch_bounds__(512) void k_finalize(const float* __restrict__ colsum,
                                                  const double* __restrict__ ssq,
                                                  float* __restrict__ mu,
                                                  float* __restrict__ invp) {
  __shared__ double sred[8];
  int j = threadIdx.x;
  float m = colsum[j] * (1.0f / 30000.0f);
  mu[j] = m;
  double p = (double)m * (double)m;
#pragma unroll
  for (int d = 1; d < 64; d <<= 1) p += __shfl_xor(p, d);
  int lane = j & 63, wid = j >> 6;
  if (lane == 0) sred[wid] = p;
  __syncthreads();
  if (j == 0) {
    double smu2 = 0.0;
#pragma unroll
    for (int w = 0; w < 8; w++) smu2 += sred[w];
    double centered = ssq[0] - 30000.0 * smu2;   // sum (x-mu)^2
    double mean = centered * (1.0 / 30000.0);
    if (!(mean >= 0.0)) mean = 0.0;              // guard
    float rn = sqrtf(1e-6f + (float)mean);
    invp[0] = 1.0f / rn;
  }
}

// ----------------------- K10: center, scale, relu (fp32) -------------------
__global__ __launch_bounds__(256) void k_finalout(const float* __restrict__ oa,
                                                  const float* __restrict__ mu,
                                                  const float* __restrict__ invp,
                                                  float* __restrict__ out) {
  size_t gid = (size_t)blockIdx.x * 256 + threadIdx.x;
  size_t i0 = gid * 4;
  if (i0 >= (size_t)N_NODES * DIM) return;
  float inv = invp[0];
  int j = (int)(i0 & (DIM - 1));
  float4 v = *(const float4*)(oa + i0);
  float4 m = *(const float4*)(mu + j);
  float4 o;
  o.x = (v.x - m.x) * inv; o.x = (o.x < 0.f) ? 0.f : o.x;
  o.y = (v.y - m.y) * inv; o.y = (o.y < 0.f) ? 0.f : o.y;
  o.z = (v.z - m.z) * inv; o.z = (o.z < 0.f) ? 0.f : o.z;
  o.w = (v.w - m.w) * inv; o.w = (o.w < 0.f) ? 0.f : o.w;
  *(float4*)(out + i0) = o;
}

// ---------------------------------------------------------------------------
extern "C" void kernel_launch(void* const* d_in, const int* in_sizes, int n_in,
                              void* d_out, int out_size, void* d_ws, size_t ws_size,
                              hipStream_t stream) {
  const float* x    = (const float*)d_in[0];
  const int*   ei   = (const int*)d_in[1];
  const float* W    = (const float*)d_in[2];
  const float* atts = (const float*)d_in[3];
  const float* attd = (const float*)d_in[4];
  const float* bias = (const float*)d_in[5];
  float* out = (float*)d_out;
  char* ws = (char*)d_ws;

  float* oa     = (float*)(ws + 0);            // 61,440,000
  u16*   xd     = (u16*)(ws + 0);              // 30,801,920 (overlay, dead after GEMM)
  u16*   h      = (u16*)(ws + 61440000);       // 30,801,920
  u16*   Wt     = (u16*)(ws + 92241920);       //    524,288
  float* a_s    = (float*)(ws + 92766208);
  float* a_d    = (float*)(ws + 92886272);
  int*   counts = (int*)(ws + 93006336);
  int*   offs   = (int*)(ws + 93126400);
  int*   cursor = (int*)(ws + 93246464);
  int*   perm   = (int*)(ws + 93366528);       //  1,320,000
  float* colsum = (float*)(ws + 94686528);
  float* mu     = (float*)(ws + 94688576);
  double* ssq   = (double*)(ws + 94690624);
  float* invp   = (float*)(ws + 94690688);     // end 94,690,752

  // d_out as scratch until k_finalout: column partials + ssq partials
  float* colpart = out;                        // 7500*512*4 = 15,360,000 B
  float* ssqpart = out + (size_t)AGG_BLOCKS * 512;  // 30,000 B

  u32 kf0, kf1, ka0, ka1;
  threefry2x32(0u, 42u, 0u, 0u, kf0, kf1);
  threefry2x32(0u, 42u, 0u, 1u, ka0, ka1);

  hipMemsetAsync(counts, 0, 120064, stream);
  hipMemsetAsync((void*)colsum, 0, 4224, stream);

  k_cvtW<<<256, 256, 0, stream>>>(W, Wt);
  k_dropout<<<7520, 256, 0, stream>>>(x, xd, kf0, kf1);
  k_gemm<<<940, 256, 0, stream>>>(xd, Wt, h);
  k_rowdots<<<7500, 256, 0, stream>>>(h, atts, attd, a_s, a_d);
  k_hist<<<1290, 256, 0, stream>>>(ei, counts);
  k_scan<<<1, 1024, 0, stream>>>(counts, offs, cursor);
  k_scatter<<<1290, 256, 0, stream>>>(ei, cursor, perm);
  k_aggregate<<<AGG_BLOCKS, 256, 0, stream>>>(ei, offs, perm, a_s, a_d, h, bias,
                                              oa, colpart, ssqpart, ka0, ka1);
  k_redstats<<<RED_BLOCKS, 256, 0, stream>>>(colpart, ssqpart, colsum, ssq);
  k_finalize<<<1, 512, 0, stream>>>(colsum, ssq, mu, invp);
  k_finalout<<<15000, 256, 0, stream>>>(oa, mu, invp, out);
}